// Round 16
// baseline (147.229 us; speedup 1.0000x reference)
//
#include <hip/hip_runtime.h>

typedef float v2f __attribute__((ext_vector_type(2)));

constexpr int NX = 192, NY = 192, NZ = 192, NB = 2;
constexpr int ZPT  = 3;            // z outputs per thread
constexpr int TZ   = NZ / ZPT;     // 64 lanes = one full z-line = one wave
constexpr int BY   = 3;            // y rows per block
constexpr int XSEG = 4;            // x outputs per block
constexpr int BLOCK_THREADS = TZ * BY;   // 192 = 3 waves, one y-row per wave
constexpr int PLANE = NY * NZ;
constexpr int NYT = NY / BY;       // 64
constexpr int NXB = NX / XSEG;     // 48
constexpr int NBLK = NYT * NXB * NB;     // 6144 blocks
constexpr int ROWS = BY + 2;             // 5 staged y-rows per tensor
constexpr int TILE_F = 2 * ROWS * NZ;    // 1920 floats = 7680 B per buffer
constexpr int SUNITS = 2 * ROWS * (NZ / 4);   // 480 float4 staging units

// full-wave DPP shifts (gfx9/CDNA): bound_ctrl=1 -> zero fill at wave edge,
// which IS the volume z-boundary here (wave spans the whole z-line).
__device__ __forceinline__ float wshr1(float v) {   // lane n <- lane n-1
    return __int_as_float(__builtin_amdgcn_update_dpp(
        0, __float_as_int(v), 0x138, 0xf, 0xf, true));
}
__device__ __forceinline__ float wshl1(float v) {   // lane n <- lane n+1
    return __int_as_float(__builtin_amdgcn_update_dpp(
        0, __float_as_int(v), 0x130, 0xf, 0xf, true));
}

// Fold one staged x-plane: 3 own-z floats per row-tensor from LDS
// (12B lane stride -> conflict-free), edge taps via DPP lane exchange.
// W01[q]/W2[q] = 3x3-window (y,z folded later/now: z here, y by row loop)
// sums for this thread's 3 z outputs.
template<bool SAFE>
__device__ __forceinline__ void foldLDS(const float* __restrict__ buf,
    int ty, int tx, const float wy[3], float wx, v2f W01[5], float W2[5])
{
    v2f S01[5], S23[5]; float S4[5];
    #pragma unroll
    for (int r = 0; r < 3; ++r) {
        const float* Lt = buf + (ty + r) * NZ + 3 * tx;   // label row
        const float* Lp = Lt + ROWS * NZ;                 // pred row
        float ta = Lt[0], tb = Lt[1], tc = Lt[2];
        float pa = Lp[0], pb = Lp[1], pc = Lp[2];
        float tm = wshr1(tc), te = wshl1(ta);   // z0-1, z0+3 (0 at volume edge)
        float pm = wshr1(pc), pe = wshl1(pa);
        if (!SAFE) {
            const float wr = wx * wy[r];        // w in {0,1} => exact masking
            tm *= wr; ta *= wr; tb *= wr; tc *= wr; te *= wr;
            pm *= wr; pa *= wr; pb *= wr; pc *= wr; pe *= wr;
        }
        const v2f T01 = v2f{tm, ta}, T23 = v2f{tb, tc};
        const v2f P01 = v2f{pm, pa}, P23 = v2f{pb, pc};
        if (r == 0) {
            S01[0] = T01;        S23[0] = T23;        S4[0] = te;
            S01[1] = P01;        S23[1] = P23;        S4[1] = pe;
            S01[2] = T01 * T01;  S23[2] = T23 * T23;  S4[2] = te * te;
            S01[3] = P01 * P01;  S23[3] = P23 * P23;  S4[3] = pe * pe;
            S01[4] = T01 * P01;  S23[4] = T23 * P23;  S4[4] = te * pe;
        } else {
            S01[0] += T01;        S23[0] += T23;        S4[0] += te;
            S01[1] += P01;        S23[1] += P23;        S4[1] += pe;
            S01[2] += T01 * T01;  S23[2] += T23 * T23;  S4[2] += te * te;
            S01[3] += P01 * P01;  S23[3] += P23 * P23;  S4[3] += pe * pe;
            S01[4] += T01 * P01;  S23[4] += T23 * P23;  S4[4] += te * pe;
        }
    }
    // z-fold: taps s0..s4 -> W0=s0+s1+s2, W1=s1+s2+s3, W2=s2+s3+s4
    #pragma unroll
    for (int q = 0; q < 5; ++q) {
        const float s0 = S01[q].x, s1 = S01[q].y, s2 = S23[q].x;
        const float s3 = S23[q].y, s4 = S4[q];
        const float m12 = s1 + s2, m34 = s3 + s4;
        W01[q] = v2f{s0 + m12, m12 + s3};
        W2[q]  = s2 + m34;
    }
}

// NCC for 3 z-outputs given full 27-voxel window sums
__device__ __forceinline__ float epilogue3(const v2f P01[5], const float P2[5],
                                           const v2f W01[5], const float W2[5])
{
    constexpr float inv_vol = 1.0f / 27.0f;
    float acc = 0.f;
    {   // packed pair (z outputs 0,1)
        const v2f st  = P01[0] + W01[0];
        const v2f sp  = P01[1] + W01[1];
        const v2f st2 = P01[2] + W01[2];
        const v2f sp2 = P01[3] + W01[3];
        const v2f stp = P01[4] + W01[4];
        const v2f tavg = st * inv_vol;
        const v2f pavg = sp * inv_vol;
        const v2f cross = stp - pavg * st;
        const v2f tvp   = st2 - tavg * st;
        const v2f pvp   = sp2 - pavg * sp;
        const v2f cc    = cross * cross;
        #pragma unroll
        for (int c = 0; c < 2; ++c) {
            const float tvar = fmaxf(tvp[c], 0.f);
            const float pvar = fmaxf(pvp[c], 0.f);
            acc += cc[c] * __builtin_amdgcn_rcpf(fmaf(tvar, pvar, 1e-5f));
        }
    }
    {   // scalar third output
        const float st  = P2[0] + W2[0];
        const float sp  = P2[1] + W2[1];
        const float st2 = P2[2] + W2[2];
        const float sp2 = P2[3] + W2[3];
        const float stp = P2[4] + W2[4];
        const float tavg = st * inv_vol;
        const float pavg = sp * inv_vol;
        const float cross = fmaf(-pavg, st, stp);
        const float tvar  = fmaxf(fmaf(-tavg, st, st2), 0.f);
        const float pvar  = fmaxf(fmaf(-pavg, sp, sp2), 0.f);
        acc += cross * cross * __builtin_amdgcn_rcpf(fmaf(tvar, pvar, 1e-5f));
    }
    return acc;
}

// March over XSEG+2 = 6 x-planes, double-buffered LDS staging (R8 skeleton).
template<bool SAFE>
__device__ __forceinline__ float march(
    const float* sb0, const float* sb1, const float* sb2, bool do3,
    int lo0, int lo1, int lo2,
    float (*tile)[TILE_F],
    int ty, int tx, const float wy[3], int xs0)
{
    v2f U01[5], V01[5], P01[5];
    float U2[5], V2[5], P2[5];
    float acc = 0.f;
    float4 G0, G1, G2;

#define XOFF(K) (SAFE ? (xs0 - 1 + (K)) * PLANE \
                      : min(max(xs0 - 1 + (K), 0), NX - 1) * PLANE)
#define WXK(K)  (SAFE ? 1.f : (((unsigned)(xs0 - 1 + (K)) < (unsigned)NX) ? 1.f : 0.f))
#define GLOAD(K) do { const int _xo = XOFF(K);                                  \
        G0 = *reinterpret_cast<const float4*>(sb0 + _xo);                       \
        G1 = *reinterpret_cast<const float4*>(sb1 + _xo);                       \
        if (do3) G2 = *reinterpret_cast<const float4*>(sb2 + _xo); } while (0)
#define DSWR(K) do { float* _d = tile[(K) & 1];                                 \
        *reinterpret_cast<float4*>(_d + lo0) = G0;                              \
        *reinterpret_cast<float4*>(_d + lo1) = G1;                              \
        if (do3) *reinterpret_cast<float4*>(_d + lo2) = G2; } while (0)
#define FOLD(K, A01, A2) foldLDS<SAFE>(tile[(K) & 1], ty, tx, wy, WXK(K), A01, A2)
#define PSET(A01, A2, B01, B2) do { _Pragma("unroll")                           \
        for (int q = 0; q < 5; ++q) { P01[q] = A01[q] + B01[q];                 \
                                      P2[q]  = A2[q]  + B2[q]; } } while (0)

    GLOAD(0); DSWR(0); __syncthreads();
    GLOAD(1); FOLD(0, U01, U2);                          DSWR(1); __syncthreads();
    GLOAD(2); FOLD(1, V01, V2); PSET(U01, U2, V01, V2);  DSWR(2); __syncthreads();
    GLOAD(3); FOLD(2, U01, U2); acc += epilogue3(P01, P2, U01, U2);
              PSET(V01, V2, U01, U2);                    DSWR(3); __syncthreads();
    GLOAD(4); FOLD(3, V01, V2); acc += epilogue3(P01, P2, V01, V2);
              PSET(U01, U2, V01, V2);                    DSWR(4); __syncthreads();
    GLOAD(5); FOLD(4, U01, U2); acc += epilogue3(P01, P2, U01, U2);
              PSET(V01, V2, U01, U2);                    DSWR(5); __syncthreads();
              FOLD(5, V01, V2); acc += epilogue3(P01, P2, V01, V2);

#undef XOFF
#undef WXK
#undef GLOAD
#undef DSWR
#undef FOLD
#undef PSET
    return acc;
}

__global__ __launch_bounds__(BLOCK_THREADS, 3)
void ncc_partial(const float* __restrict__ pred, const float* __restrict__ label,
                 float* __restrict__ partials)
{
    __shared__ alignas(16) float tile[2][TILE_F];    // 15,360 B

    const int tx  = threadIdx.x;                     // 0..63: z-line lane
    const int ty  = threadIdx.y;                     // 0..2:  y row (one per wave)
    const int tid = tx + ty * TZ;
    const int Y0  = blockIdx.x * BY;
    const int y   = Y0 + ty;
    const int xs0 = blockIdx.y * XSEG;
    const int b   = blockIdx.z;
    const int bbase = b * NX * PLANE;

    // staging: 480 float4 units = [tensor 2][row 5][z4 48]; thread does <=3
    const float* sb[3]; int lo[3];
    #pragma unroll
    for (int k = 0; k < 3; ++k) {
        const int u  = tid + k * BLOCK_THREADS;
        const int uu = (u < SUNITS) ? u : 0;
        const int tt  = uu / 240;
        const int rem = uu - tt * 240;
        const int row = rem / 48;
        const int z4  = rem - row * 48;
        const int grow = min(max(Y0 - 1 + row, 0), NY - 1);
        sb[k] = (tt ? pred : label) + bbase + grow * NZ + z4 * 4;
        lo[k] = (tt * ROWS + row) * NZ + z4 * 4;
    }
    const bool do3 = (tid < SUNITS - 2 * BLOCK_THREADS);   // tid < 96

    float wy[3];
    #pragma unroll
    for (int r = 0; r < 3; ++r) {
        const int yy = y + r - 1;
        wy[r] = ((unsigned)yy < (unsigned)NY) ? 1.f : 0.f;
    }

    const bool safe = (blockIdx.x >= 1) && (blockIdx.x <= NYT - 2) &&
                      (blockIdx.y >= 1) && (blockIdx.y <= NXB - 2);

    const float acc = safe
        ? march<true >(sb[0], sb[1], sb[2], do3, lo[0], lo[1], lo[2], tile,
                       ty, tx, wy, xs0)
        : march<false>(sb[0], sb[1], sb[2], do3, lo[0], lo[1], lo[2], tile,
                       ty, tx, wy, xs0);

    // wave (64) reduction, then block sum
    float a = acc;
    #pragma unroll
    for (int o = 32; o > 0; o >>= 1)
        a += __shfl_down(a, o, 64);

    __shared__ float wsum[BLOCK_THREADS / 64];
    if ((tid & 63) == 0) wsum[tid >> 6] = a;
    __syncthreads();
    if (tid == 0) {
        float s = 0.f;
        #pragma unroll
        for (int w = 0; w < BLOCK_THREADS / 64; ++w) s += wsum[w];
        partials[blockIdx.x + (int)gridDim.x * (blockIdx.y + (int)gridDim.y * blockIdx.z)] = s;
    }
}

__global__ __launch_bounds__(256)
void ncc_reduce(const float* __restrict__ partials, int n, float* __restrict__ out)
{
    __shared__ double sh[256];
    double s = 0.0;
    for (int i = threadIdx.x; i < n; i += 256) s += (double)partials[i];
    sh[threadIdx.x] = s;
    __syncthreads();
    for (int off = 128; off > 0; off >>= 1) {
        if ((int)threadIdx.x < off) sh[threadIdx.x] += sh[threadIdx.x + off];
        __syncthreads();
    }
    if (threadIdx.x == 0) {
        const double nvox = (double)NB * NX * NY * NZ;
        out[0] = (float)(-sh[0] / nvox);
    }
}

extern "C" void kernel_launch(void* const* d_in, const int* in_sizes, int n_in,
                              void* d_out, int out_size, void* d_ws, size_t ws_size,
                              hipStream_t stream) {
    const float* pred  = (const float*)d_in[0];
    const float* label = (const float*)d_in[1];
    float* out = (float*)d_out;
    float* partials = (float*)d_ws;

    dim3 block(TZ, BY, 1);                 // 64 x 3 = 192 threads
    dim3 grid(NYT, NXB, NB);               // 64 x 48 x 2 = 6144 blocks

    ncc_partial<<<grid, block, 0, stream>>>(pred, label, partials);
    ncc_reduce<<<1, 256, 0, stream>>>(partials, NBLK, out);
}

// Round 17
// 72.370 us; speedup vs baseline: 2.0344x; 2.0344x over previous
//
#include <hip/hip_runtime.h>

typedef float v2f __attribute__((ext_vector_type(2)));

constexpr int NX = 192, NY = 192, NZ = 192, NB = 2;
constexpr int ZPT  = 3;            // z outputs per thread
constexpr int TZ   = NZ / ZPT;     // 64 lanes = one full z-line = one wave
constexpr int BY   = 6;            // y rows per block (one per wave)
constexpr int XSEG = 4;            // x outputs per block
constexpr int BLOCK_THREADS = TZ * BY;   // 384 = 6 waves
constexpr int PLANE = NY * NZ;
constexpr int NYT = NY / BY;       // 32
constexpr int NXB = NX / XSEG;     // 48
constexpr int NBLK = NYT * NXB * NB;     // 3072 blocks
constexpr int ROWS = BY + 2;             // 8 staged y-rows per tensor
constexpr int TILE_F = 2 * ROWS * NZ;    // 3072 floats = 12,288 B per buffer
// staging: 2 tensors x 8 rows x 48 float4 = 768 units = exactly 2 per thread

// full-wave DPP shifts (gfx9/CDNA): bound_ctrl=1 -> zero fill at wave edge,
// which IS the volume z-boundary (wave spans the whole z-line). Verified
// correct in R16 (absmax = 0).
__device__ __forceinline__ float wshr1(float v) {   // lane n <- lane n-1
    return __int_as_float(__builtin_amdgcn_update_dpp(
        0, __float_as_int(v), 0x138, 0xf, 0xf, true));
}
__device__ __forceinline__ float wshl1(float v) {   // lane n <- lane n+1
    return __int_as_float(__builtin_amdgcn_update_dpp(
        0, __float_as_int(v), 0x130, 0xf, 0xf, true));
}

// Fold one staged x-plane. Own-z reads only: 3 b32 at 12B lane stride
// (conflict-free: bank = 3*tx mod 32, gcd(3,32)=1 -> 2 lanes/bank).
// Edge taps z0-1 / z0+3 via DPP lane exchange (VALU pipe, zero LDS cost).
// Output shape identical to the never-spilling R8/R13 kernel: v2f W[5][2],
// with the 4th slot zeroed (contributes exactly 0 in epilogue4).
template<bool SAFE>
__device__ __forceinline__ void foldLDS(const float* __restrict__ buf,
    int ty, int tx, const float wy[3], float wx, v2f W[5][2])
{
    v2f SA[5], SB[5]; float SE[5];
    #pragma unroll
    for (int r = 0; r < 3; ++r) {
        const float* Lt = buf + (ty + r) * NZ + 3 * tx;   // label row
        const float* Lp = Lt + ROWS * NZ;                 // pred row
        float ta = Lt[0], tb = Lt[1], tc = Lt[2];
        float pa = Lp[0], pb = Lp[1], pc = Lp[2];
        float tm = wshr1(tc), te = wshl1(ta);   // z0-1, z0+3 (0 at volume edge)
        float pm = wshr1(pc), pe = wshl1(pa);
        if (!SAFE) {
            const float wr = wx * wy[r];        // w in {0,1} => exact masking
            tm *= wr; ta *= wr; tb *= wr; tc *= wr; te *= wr;
            pm *= wr; pa *= wr; pb *= wr; pc *= wr; pe *= wr;
        }
        const v2f TA = v2f{tm, ta}, TB = v2f{tb, tc};
        const v2f PA = v2f{pm, pa}, PB = v2f{pb, pc};
        if (r == 0) {
            SA[0] = TA;       SB[0] = TB;       SE[0] = te;
            SA[1] = PA;       SB[1] = PB;       SE[1] = pe;
            SA[2] = TA * TA;  SB[2] = TB * TB;  SE[2] = te * te;
            SA[3] = PA * PA;  SB[3] = PB * PB;  SE[3] = pe * pe;
            SA[4] = TA * PA;  SB[4] = TB * PB;  SE[4] = te * pe;
        } else {
            SA[0] += TA;       SB[0] += TB;       SE[0] += te;
            SA[1] += PA;       SB[1] += PB;       SE[1] += pe;
            SA[2] += TA * TA;  SB[2] += TB * TB;  SE[2] += te * te;
            SA[3] += PA * PA;  SB[3] += PB * PB;  SE[3] += pe * pe;
            SA[4] += TA * PA;  SB[4] += TB * PB;  SE[4] += te * pe;
        }
    }
    // z-fold: taps s0..s4 -> w0=s0+s1+s2, w1=s1+s2+s3, w2=s2+s3+s4
    #pragma unroll
    for (int q = 0; q < 5; ++q) {
        const float s0 = SA[q].x, s1 = SA[q].y, s2 = SB[q].x;
        const float s3 = SB[q].y, s4 = SE[q];
        const float m12 = s1 + s2, m34 = s3 + s4;
        W[q][0] = v2f{s0 + m12, m12 + s3};
        W[q][1] = v2f{s2 + m34, 0.f};
    }
}

// R13's epilogue verbatim; 4th slot is all-zero -> cross=0, vars=0 -> adds 0.
__device__ __forceinline__ float epilogue4(const v2f P[5][2], const v2f Wn[5][2])
{
    constexpr float inv_vol = 1.0f / 27.0f;
    float acc = 0.f;
    #pragma unroll
    for (int h = 0; h < 2; ++h) {
        const v2f st  = P[0][h] + Wn[0][h];
        const v2f sp  = P[1][h] + Wn[1][h];
        const v2f st2 = P[2][h] + Wn[2][h];
        const v2f sp2 = P[3][h] + Wn[3][h];
        const v2f stp = P[4][h] + Wn[4][h];
        const v2f tavg = st * inv_vol;
        const v2f pavg = sp * inv_vol;
        const v2f cross = stp - pavg * st;
        const v2f tvp   = st2 - tavg * st;
        const v2f pvp   = sp2 - pavg * sp;
        const v2f cc    = cross * cross;
        #pragma unroll
        for (int c = 0; c < 2; ++c) {
            const float tvar = fmaxf(tvp[c], 0.f);
            const float pvar = fmaxf(pvp[c], 0.f);
            acc += cc[c] * __builtin_amdgcn_rcpf(fmaf(tvar, pvar, 1e-5f));
        }
    }
    return acc;
}

// R8/R13's proven 6-plane double-buffered march, 2 staging units per thread.
template<bool SAFE>
__device__ __forceinline__ float march(
    const float* sb0, const float* sb1,      // label/pred staging srcs (sans x)
    int lo0, int lo1,                        // LDS float offsets
    float (*tile)[TILE_F],
    int ty, int tx, const float wy[3], int xs0)
{
    v2f U[5][2], V[5][2], P[5][2];
    float acc = 0.f;
    float4 G0, G1;

#define XOFF(K) (SAFE ? (xs0 - 1 + (K)) * PLANE \
                      : min(max(xs0 - 1 + (K), 0), NX - 1) * PLANE)
#define WXK(K)  (SAFE ? 1.f : (((unsigned)(xs0 - 1 + (K)) < (unsigned)NX) ? 1.f : 0.f))
#define GLOAD(K) do { const int _xo = XOFF(K);                                  \
        G0 = *reinterpret_cast<const float4*>(sb0 + _xo);                       \
        G1 = *reinterpret_cast<const float4*>(sb1 + _xo); } while (0)
#define DSWR(K) do { float* _d = tile[(K) & 1];                                 \
        *reinterpret_cast<float4*>(_d + lo0) = G0;                              \
        *reinterpret_cast<float4*>(_d + lo1) = G1; } while (0)
#define FOLD(K, WDST) foldLDS<SAFE>(tile[(K) & 1], ty, tx, wy, WXK(K), WDST)
#define PSET(A, B) do { _Pragma("unroll")                                       \
        for (int q = 0; q < 5; ++q) { _Pragma("unroll")                         \
            for (int h = 0; h < 2; ++h) P[q][h] = A[q][h] + B[q][h]; } } while (0)

    GLOAD(0); DSWR(0); __syncthreads();
    GLOAD(1); FOLD(0, U);             DSWR(1); __syncthreads();
    GLOAD(2); FOLD(1, V); PSET(U, V); DSWR(2); __syncthreads();
    GLOAD(3); FOLD(2, U); acc += epilogue4(P, U); PSET(V, U); DSWR(3); __syncthreads();
    GLOAD(4); FOLD(3, V); acc += epilogue4(P, V); PSET(U, V); DSWR(4); __syncthreads();
    GLOAD(5); FOLD(4, U); acc += epilogue4(P, U); PSET(V, U); DSWR(5); __syncthreads();
              FOLD(5, V); acc += epilogue4(P, V);

#undef XOFF
#undef WXK
#undef GLOAD
#undef DSWR
#undef FOLD
#undef PSET
    return acc;
}

__global__ __launch_bounds__(BLOCK_THREADS, 3)
void ncc_partial(const float* __restrict__ pred, const float* __restrict__ label,
                 float* __restrict__ partials)
{
    __shared__ alignas(16) float tile[2][TILE_F];    // 24,576 B

    const int tx  = threadIdx.x;                     // 0..63: z-line lane
    const int ty  = threadIdx.y;                     // 0..5:  y row (one per wave)
    const int tid = tx + ty * TZ;
    const int Y0  = blockIdx.x * BY;
    const int y   = Y0 + ty;
    const int xs0 = blockIdx.y * XSEG;
    const int b   = blockIdx.z;
    const int bbase = b * NX * PLANE;

    // staging: unit tid of [row 8][z4 48] per tensor; label (k=0) & pred (k=1)
    // share the same row/z4 -> one offset pair serves both.
    const int row = tid / 48;
    const int z4  = tid - row * 48;
    const int grow = min(max(Y0 - 1 + row, 0), NY - 1);
    const float* sb0 = label + bbase + grow * NZ + z4 * 4;
    const float* sb1 = pred  + bbase + grow * NZ + z4 * 4;
    const int lo0 = row * NZ + z4 * 4;
    const int lo1 = lo0 + ROWS * NZ;

    float wy[3];
    #pragma unroll
    for (int r = 0; r < 3; ++r) {
        const int yy = y + r - 1;
        wy[r] = ((unsigned)yy < (unsigned)NY) ? 1.f : 0.f;
    }

    const bool safe = (blockIdx.x >= 1) && (blockIdx.x <= NYT - 2) &&
                      (blockIdx.y >= 1) && (blockIdx.y <= NXB - 2);

    const float acc = safe
        ? march<true >(sb0, sb1, lo0, lo1, tile, ty, tx, wy, xs0)
        : march<false>(sb0, sb1, lo0, lo1, tile, ty, tx, wy, xs0);

    // wave (64) reduction, then block sum
    float a = acc;
    #pragma unroll
    for (int o = 32; o > 0; o >>= 1)
        a += __shfl_down(a, o, 64);

    __shared__ float wsum[BLOCK_THREADS / 64];
    if ((tid & 63) == 0) wsum[tid >> 6] = a;
    __syncthreads();
    if (tid == 0) {
        float s = 0.f;
        #pragma unroll
        for (int w = 0; w < BLOCK_THREADS / 64; ++w) s += wsum[w];
        partials[blockIdx.x + (int)gridDim.x * (blockIdx.y + (int)gridDim.y * blockIdx.z)] = s;
    }
}

__global__ __launch_bounds__(256)
void ncc_reduce(const float* __restrict__ partials, int n, float* __restrict__ out)
{
    __shared__ double sh[256];
    double s = 0.0;
    for (int i = threadIdx.x; i < n; i += 256) s += (double)partials[i];
    sh[threadIdx.x] = s;
    __syncthreads();
    for (int off = 128; off > 0; off >>= 1) {
        if ((int)threadIdx.x < off) sh[threadIdx.x] += sh[threadIdx.x + off];
        __syncthreads();
    }
    if (threadIdx.x == 0) {
        const double nvox = (double)NB * NX * NY * NZ;
        out[0] = (float)(-sh[0] / nvox);
    }
}

extern "C" void kernel_launch(void* const* d_in, const int* in_sizes, int n_in,
                              void* d_out, int out_size, void* d_ws, size_t ws_size,
                              hipStream_t stream) {
    const float* pred  = (const float*)d_in[0];
    const float* label = (const float*)d_in[1];
    float* out = (float*)d_out;
    float* partials = (float*)d_ws;

    dim3 block(TZ, BY, 1);                 // 64 x 6 = 384 threads
    dim3 grid(NYT, NXB, NB);               // 32 x 48 x 2 = 3072 blocks

    ncc_partial<<<grid, block, 0, stream>>>(pred, label, partials);
    ncc_reduce<<<1, 256, 0, stream>>>(partials, NBLK, out);
}